// Round 1
// baseline (615.947 us; speedup 1.0000x reference)
//
#include <hip/hip_runtime.h>
#include <math.h>

// GATConv factorized:
//   h = x@W + b                       [N,128] viewed [N,4,32]
//   s[n,h] = <h[n,h,:], att_src[h]>   t[n,h] = <h[n,h,:], att_dst[h]>
//   last[n] = max edge id e with src[e]==n  (JAX "last write wins")
//   dense[n,h] = leaky_relu(s[n] + t[dst[last[n]]] + edgeMLP(edge_attr[last[n]])), else -inf
//   softmax over node axis (global per head)
//   out[n,f] = (1/4) sum_h dense_soft[n,h] * sum_{e:src=n} h[dst[e],h*32+f]

__global__ void k_gemm(const float* __restrict__ x, const float* __restrict__ W,
                       const float* __restrict__ b, float* __restrict__ hbuf, int N) {
  __shared__ float xs[16 * 128];
  int tx = threadIdx.x;
  int r0 = blockIdx.x * 16;
  const float4* xg = (const float4*)(x + (size_t)r0 * 128);
  float4* xs4 = (float4*)xs;
#pragma unroll
  for (int j = 0; j < 2; ++j) {
    int l = tx + j * 256;          // 512 float4 = 16 rows * 128 floats
    int row = l >> 5;
    if (r0 + row < N) xs4[l] = xg[l];
  }
  __syncthreads();
  int c4 = (tx & 31) * 4;          // 4 contiguous output cols
  int rg = tx >> 5;                // 8 groups -> rows rg*2, rg*2+1
  float acc0[4] = {0, 0, 0, 0}, acc1[4] = {0, 0, 0, 0};
  const float* xr0 = xs + (rg * 2) * 128;
  const float* xr1 = xs + (rg * 2 + 1) * 128;
#pragma unroll 4
  for (int k = 0; k < 128; ++k) {
    float4 w4 = *(const float4*)(W + (size_t)k * 128 + c4);
    float xa = xr0[k], xb = xr1[k];
    acc0[0] += xa * w4.x; acc0[1] += xa * w4.y; acc0[2] += xa * w4.z; acc0[3] += xa * w4.w;
    acc1[0] += xb * w4.x; acc1[1] += xb * w4.y; acc1[2] += xb * w4.z; acc1[3] += xb * w4.w;
  }
  float4 bb = *(const float4*)(b + c4);
  int gr0 = r0 + rg * 2, gr1 = gr0 + 1;
  if (gr0 < N) {
    float4 o; o.x = acc0[0] + bb.x; o.y = acc0[1] + bb.y; o.z = acc0[2] + bb.z; o.w = acc0[3] + bb.w;
    *(float4*)(hbuf + (size_t)gr0 * 128 + c4) = o;
  }
  if (gr1 < N) {
    float4 o; o.x = acc1[0] + bb.x; o.y = acc1[1] + bb.y; o.z = acc1[2] + bb.z; o.w = acc1[3] + bb.w;
    *(float4*)(hbuf + (size_t)gr1 * 128 + c4) = o;
  }
}

__global__ void k_scores(const float* __restrict__ hbuf, const float* __restrict__ att_src,
                         const float* __restrict__ att_dst, float* __restrict__ s_,
                         float* __restrict__ t_, int N) {
  int idx = blockIdx.x * blockDim.x + threadIdx.x;
  if (idx >= N * 4) return;
  int n = idx >> 2, hd = idx & 3;
  const float4* hp = (const float4*)(hbuf + (size_t)n * 128 + hd * 32);
  const float4* as = (const float4*)(att_src + hd * 32);
  const float4* ad = (const float4*)(att_dst + hd * 32);
  float ss = 0.f, tt = 0.f;
#pragma unroll
  for (int i = 0; i < 8; ++i) {
    float4 hv = hp[i], a = as[i], d = ad[i];
    ss += hv.x * a.x + hv.y * a.y + hv.z * a.z + hv.w * a.w;
    tt += hv.x * d.x + hv.y * d.y + hv.z * d.z + hv.w * d.w;
  }
  s_[idx] = ss;
  t_[idx] = tt;
}

__global__ void k_hist(const int* __restrict__ src, int* __restrict__ deg,
                       int* __restrict__ last, int E) {
  int e = blockIdx.x * blockDim.x + threadIdx.x;
  if (e < E) {
    int s = src[e];
    atomicAdd(&deg[s], 1);
    atomicMax(&last[s], e);
  }
}

__global__ void k_scan1(const int* __restrict__ deg, int* __restrict__ tmp,
                        int* __restrict__ bsum, int N) {
  __shared__ int lds[1024];
  int tx = threadIdx.x;
  int i = blockIdx.x * 1024 + tx;
  int v = (i < N) ? deg[i] : 0;
  lds[tx] = v;
  __syncthreads();
  for (int off = 1; off < 1024; off <<= 1) {
    int t = (tx >= off) ? lds[tx - off] : 0;
    __syncthreads();
    lds[tx] += t;
    __syncthreads();
  }
  if (i < N) tmp[i] = lds[tx];
  if (tx == 1023) bsum[blockIdx.x] = lds[1023];
}

__global__ void k_scan2(const int* __restrict__ bsum, int* __restrict__ boff, int nb) {
  if (blockIdx.x == 0 && threadIdx.x == 0) {
    int run = 0;
    for (int j = 0; j < nb; ++j) { boff[j] = run; run += bsum[j]; }
  }
}

__global__ void k_scan3(const int* __restrict__ tmp, const int* __restrict__ deg,
                        const int* __restrict__ boff, int* __restrict__ rowptr,
                        int* __restrict__ cur, int N, int E) {
  int i = blockIdx.x * 1024 + threadIdx.x;
  if (i < N) {
    int r = tmp[i] - deg[i] + boff[i >> 10];
    rowptr[i] = r;
    cur[i] = r;
  }
  if (i == 0) rowptr[N] = E;
}

__global__ void k_scatter(const int* __restrict__ src, const int* __restrict__ dst,
                          int* __restrict__ cur, int* __restrict__ col, int E) {
  int e = blockIdx.x * blockDim.x + threadIdx.x;
  if (e < E) {
    int s = src[e];
    int pos = atomicAdd(&cur[s], 1);
    col[pos] = dst[e];
  }
}

__global__ void k_dense(const int* __restrict__ last, const int* __restrict__ dst,
                        const float* __restrict__ edge_attr,
                        const float* __restrict__ eW1, const float* __restrict__ eb1,
                        const float* __restrict__ eW2, const float* __restrict__ eb2,
                        const float* __restrict__ s_, const float* __restrict__ t_,
                        float* __restrict__ dense, int N) {
  int n = blockIdx.x * blockDim.x + threadIdx.x;
  if (n >= N) return;
  int e = last[n];
  if (e < 0) {
    dense[n * 4 + 0] = -INFINITY; dense[n * 4 + 1] = -INFINITY;
    dense[n * 4 + 2] = -INFINITY; dense[n * 4 + 3] = -INFINITY;
    return;
  }
  int d = dst[e];
  const float* ea = edge_attr + (size_t)e * 4;
  float e0 = ea[0], e1 = ea[1], e2 = ea[2], e3 = ea[3];
  float a0 = eb2[0], a1 = eb2[1], a2 = eb2[2], a3 = eb2[3];
#pragma unroll
  for (int i = 0; i < 32; ++i) {
    float hid = eb1[i] + e0 * eW1[i] + e1 * eW1[32 + i] + e2 * eW1[64 + i] + e3 * eW1[96 + i];
    hid = fmaxf(hid, 0.f);
    a0 += hid * eW2[i * 4 + 0]; a1 += hid * eW2[i * 4 + 1];
    a2 += hid * eW2[i * 4 + 2]; a3 += hid * eW2[i * 4 + 3];
  }
  float v0 = s_[n * 4 + 0] + t_[d * 4 + 0] + a0;
  float v1 = s_[n * 4 + 1] + t_[d * 4 + 1] + a1;
  float v2 = s_[n * 4 + 2] + t_[d * 4 + 2] + a2;
  float v3 = s_[n * 4 + 3] + t_[d * 4 + 3] + a3;
  dense[n * 4 + 0] = v0 > 0.f ? v0 : 0.2f * v0;
  dense[n * 4 + 1] = v1 > 0.f ? v1 : 0.2f * v1;
  dense[n * 4 + 2] = v2 > 0.f ? v2 : 0.2f * v2;
  dense[n * 4 + 3] = v3 > 0.f ? v3 : 0.2f * v3;
}

// online-softmax partial reduction over node axis, per head
__global__ void k_smax1(const float* __restrict__ dense, int N,
                        float* __restrict__ pmax, float* __restrict__ psum) {
  float m[4], s[4];
#pragma unroll
  for (int h = 0; h < 4; ++h) { m[h] = -INFINITY; s[h] = 0.f; }
  for (int n = blockIdx.x * blockDim.x + threadIdx.x; n < N; n += gridDim.x * blockDim.x) {
#pragma unroll
    for (int h = 0; h < 4; ++h) {
      float v = dense[n * 4 + h];
      float nm = fmaxf(m[h], v);
      if (nm > -INFINITY) {
        s[h] = s[h] * expf(m[h] - nm) + expf(v - nm);
        m[h] = nm;
      }
    }
  }
  __shared__ float lm[256 * 4], lss[256 * 4];
  int tx = threadIdx.x;
#pragma unroll
  for (int h = 0; h < 4; ++h) { lm[tx * 4 + h] = m[h]; lss[tx * 4 + h] = s[h]; }
  __syncthreads();
  for (int off = 128; off > 0; off >>= 1) {
    if (tx < off) {
#pragma unroll
      for (int h = 0; h < 4; ++h) {
        float m2 = lm[(tx + off) * 4 + h], s2 = lss[(tx + off) * 4 + h];
        float m1 = lm[tx * 4 + h], s1 = lss[tx * 4 + h];
        float M = fmaxf(m1, m2);
        if (M > -INFINITY) {
          lss[tx * 4 + h] = s1 * expf(m1 - M) + s2 * expf(m2 - M);
          lm[tx * 4 + h] = M;
        }
      }
    }
    __syncthreads();
  }
  if (tx == 0) {
#pragma unroll
    for (int h = 0; h < 4; ++h) {
      pmax[blockIdx.x * 4 + h] = lm[h];
      psum[blockIdx.x * 4 + h] = lss[h];
    }
  }
}

__global__ void k_smax2(const float* __restrict__ pmax, const float* __restrict__ psum,
                        int nb, float* __restrict__ gmax, float* __restrict__ ginv) {
  int h = threadIdx.x;
  if (h < 4) {
    float m = -INFINITY, s = 0.f;
    for (int bq = 0; bq < nb; ++bq) {
      float m2 = pmax[bq * 4 + h], s2 = psum[bq * 4 + h];
      float M = fmaxf(m, m2);
      if (M > -INFINITY) {
        s = s * expf(m - M) + s2 * expf(m2 - M);
        m = M;
      }
    }
    gmax[h] = m;
    ginv[h] = 1.f / s;
  }
}

// one block (128 threads) per node: gather-sum neighbor h rows, scale, head-mean
__global__ void k_agg(const int* __restrict__ rowptr, const int* __restrict__ col,
                      const float* __restrict__ hbuf, const float* __restrict__ dense,
                      const float* __restrict__ gmax, const float* __restrict__ ginv,
                      float* __restrict__ out, int N) {
  int n = blockIdx.x;
  int tx = threadIdx.x;
  int beg = rowptr[n], end = rowptr[n + 1];
  float acc = 0.f;
  for (int e = beg; e < end; ++e) {
    int c = col[e];
    acc += hbuf[(size_t)c * 128 + tx];
  }
  int hd = tx >> 5;
  float w = expf(dense[n * 4 + hd] - gmax[hd]) * ginv[hd];
  __shared__ float lds[128];
  lds[tx] = acc * w;
  __syncthreads();
  if (tx < 32) {
    out[(size_t)n * 32 + tx] = 0.25f * (lds[tx] + lds[tx + 32] + lds[tx + 64] + lds[tx + 96]);
  }
}

extern "C" void kernel_launch(void* const* d_in, const int* in_sizes, int n_in,
                              void* d_out, int out_size, void* d_ws, size_t ws_size,
                              hipStream_t stream) {
  const float* x        = (const float*)d_in[0];
  const int*   ei       = (const int*)d_in[1];
  const float* edge_attr= (const float*)d_in[2];
  const float* W        = (const float*)d_in[3];
  const float* b        = (const float*)d_in[4];
  const float* eW1      = (const float*)d_in[5];
  const float* eb1      = (const float*)d_in[6];
  const float* eW2      = (const float*)d_in[7];
  const float* eb2      = (const float*)d_in[8];
  const float* att_src  = (const float*)d_in[9];
  const float* att_dst  = (const float*)d_in[10];
  float* out = (float*)d_out;

  const int N = in_sizes[0] / 128;
  const int E = in_sizes[1] / 2;
  const int* src = ei;
  const int* dst = ei + E;

  char* wp = (char*)d_ws;
  auto alloc = [&](size_t bytes) -> void* {
    void* p = (void*)wp;
    wp += (bytes + 255) & ~(size_t)255;
    return p;
  };
  float* hbuf  = (float*)alloc((size_t)N * 128 * 4);
  float* s_    = (float*)alloc((size_t)N * 4 * 4);
  float* t_    = (float*)alloc((size_t)N * 4 * 4);
  float* dense = (float*)alloc((size_t)N * 4 * 4);
  float* pmax  = (float*)alloc(64 * 4 * 4);
  float* psum  = (float*)alloc(64 * 4 * 4);
  float* gmax  = (float*)alloc(4 * 4);
  float* ginv  = (float*)alloc(4 * 4);
  int* last    = (int*)alloc((size_t)N * 4);
  int* deg     = (int*)alloc((size_t)N * 4);
  int* tmp     = (int*)alloc((size_t)N * 4);
  int* bsum    = (int*)alloc(64 * 4);
  int* boff    = (int*)alloc(64 * 4);
  int* rowptr  = (int*)alloc((size_t)(N + 1) * 4);
  int* cur     = (int*)alloc((size_t)N * 4);
  int* col     = (int*)alloc((size_t)E * 4);

  hipMemsetAsync(last, 0xFF, (size_t)N * 4, stream);  // -1
  hipMemsetAsync(deg, 0, (size_t)N * 4, stream);

  k_gemm<<<(N + 15) / 16, 256, 0, stream>>>(x, W, b, hbuf, N);
  k_scores<<<(N * 4 + 255) / 256, 256, 0, stream>>>(hbuf, att_src, att_dst, s_, t_, N);
  k_hist<<<(E + 255) / 256, 256, 0, stream>>>(src, deg, last, E);

  int nb = (N + 1023) / 1024;
  k_scan1<<<nb, 1024, 0, stream>>>(deg, tmp, bsum, N);
  k_scan2<<<1, 64, 0, stream>>>(bsum, boff, nb);
  k_scan3<<<nb, 1024, 0, stream>>>(tmp, deg, boff, rowptr, cur, N, E);
  k_scatter<<<(E + 255) / 256, 256, 0, stream>>>(src, dst, cur, col, E);

  k_dense<<<(N + 255) / 256, 256, 0, stream>>>(last, dst, edge_attr, eW1, eb1, eW2, eb2,
                                               s_, t_, dense, N);
  k_smax1<<<64, 256, 0, stream>>>(dense, N, pmax, psum);
  k_smax2<<<1, 64, 0, stream>>>(pmax, psum, 64, gmax, ginv);

  k_agg<<<N, 128, 0, stream>>>(rowptr, col, hbuf, dense, gmax, ginv, out, N);
}